// Round 1
// baseline (234.549 us; speedup 1.0000x reference)
//
#include <hip/hip_runtime.h>

#define IMG_H 1080
#define IMG_W 1920
#define TILE_W 256              // 32 threads * 8 px
#define TILE_H 8
#define GXB ((IMG_W + TILE_W - 1) / TILE_W)   // 8
#define GYB (IMG_H / TILE_H)                  // 135

// Nonzero iff the 16-bit circular mask has 9 consecutive set bits.
// (Validated absmax=0 in prior rounds; unchanged.)
__device__ __forceinline__ unsigned det9(unsigned m) {
    unsigned x = m | (m << 16);
    unsigned t = x & (x >> 1);   // run 2
    t &= t >> 2;                 // run 4
    t &= t >> 4;                 // run 8
    t &= x >> 8;                 // run 9
    return t;
}

// m = (m << 1) | (val CMP thr) in exactly 2 VALU (v_cmp + v_addc m+m+carry).
#define STEP_GE(m, sc, val, thr)                                          \
    asm("v_cmp_ge_f32 %1, %2, %3\n\tv_addc_co_u32 %0, %1, %0, %0, %1"     \
        : "+v"(m), "=s"(sc) : "v"(val), "v"(thr))
#define STEP_LE(m, sc, val, thr)                                          \
    asm("v_cmp_le_f32 %1, %2, %3\n\tv_addc_co_u32 %0, %1, %0, %0, %1"     \
        : "+v"(m), "=s"(sc) : "v"(val), "v"(thr))

// Compile-time-constant float4 component access (keeps arrays in registers,
// avoids scratch per rule: no runtime-indexed vector arrays).
__device__ __forceinline__ float f4_get(const float4& v, int c) {
    return c == 0 ? v.x : c == 1 ? v.y : c == 2 ? v.z : v.w;
}
__device__ __forceinline__ void f4_set(float4& v, int c, float x) {
    if (c == 0) v.x = x; else if (c == 1) v.y = x; else if (c == 2) v.z = x; else v.w = x;
}

__global__ __launch_bounds__(256) void fast_score_kernel(const float* __restrict__ img,
                                                         float* __restrict__ out) {
    // Flat block id -> bijective XCD swizzle (grid % 8 == 0: 8*135*n_img).
    int bid = blockIdx.x;
    const int nwg = gridDim.x;
    if ((nwg & 7) == 0) {
        bid = (bid & 7) * (nwg >> 3) + (bid >> 3);
    }
    const int bx  = bid % GXB;          // 0..7   (x tile)
    const int byz = bid / GXB;
    const int by  = byz % GYB;          // 0..134 (y band)
    const int n   = byz / GYB;          // image

    const int tx = threadIdx.x;         // 0..31
    const int ty = threadIdx.y;         // 0..7

    const int gx0 = bx * TILE_W + tx * 8;   // first of this thread's 8 pixels
    const int y   = by * TILE_H + ty;       // output row (grid covers 1080 exactly)

    const float* base = img + (size_t)n * (IMG_H * IMG_W);

    // 7 replicate-clamped row pointers (per-thread; rows y-3..y+3).
    const float* rp[7];
#pragma unroll
    for (int d = 0; d < 7; ++d) {
        const int ry = min(max(y + d - 3, 0), IMG_H - 1);
        rp[d] = base + (size_t)ry * IMG_W;
    }

    // 16-float window [c0, c0+15] covers cols gx0-3 .. gx0+10 (indices 1..14).
    // c0 = gx0-4 is 16B-aligned (gx0 % 8 == 0).
    const int c0 = gx0 - 4;
    float4 r[7][4];
    if (c0 >= 0 && c0 + 16 <= IMG_W) {
        // Fast path: 28 aligned dwordx4 loads, all independent.
#pragma unroll
        for (int d = 0; d < 7; ++d) {
            const float4* p = (const float4*)(rp[d] + c0);
            r[d][0] = p[0];
            r[d][1] = p[1];
            r[d][2] = p[2];
            r[d][3] = p[3];
        }
    } else {
        // Edge path (x-border threads only): per-element replicate clamp.
#pragma unroll
        for (int d = 0; d < 7; ++d) {
#pragma unroll
            for (int j = 0; j < 16; ++j) {
                const int cc = min(max(c0 + j, 0), IMG_W - 1);
                f4_set(r[d][j >> 2], j & 3, rp[d][cc]);
            }
        }
    }

    constexpr int DY[16] = {0, 1, 2, 3, 3, 3, 2, 1, 0, -1, -2, -3, -3, -3, -2, -1};
    constexpr int DX[16] = {-3, -3, -2, -1, 0, 1, 2, 3, 3, 3, 2, 1, 0, -1, -2, -3};

    float res[8];
#pragma unroll
    for (int i = 0; i < 8; ++i) {
        const float center = f4_get(r[3][(i + 4) >> 2], (i + 4) & 3);
        const float hi = center + 20.0f;
        const float lo = center - 20.0f;
        unsigned dark = 0u, bright = 0u;
        unsigned long long sc0, sc1;
#pragma unroll
        for (int k = 0; k < 16; ++k) {
            const int w = i + DX[k] + 4;          // compile-time after unroll
            const float t = f4_get(r[DY[k] + 3][w >> 2], w & 3);
            STEP_GE(dark,   sc0, t, hi);
            STEP_LE(bright, sc1, t, lo);
        }
        res[i] = (det9(dark) | det9(bright)) ? 1.0f : 0.0f;
    }

    // W % 8 == 0, so a thread is either fully active or fully inactive.
    if (gx0 < IMG_W) {
        float* o = out + (size_t)n * (IMG_H * IMG_W) + (size_t)y * IMG_W + gx0;
        *(float4*)(o)     = make_float4(res[0], res[1], res[2], res[3]);
        *(float4*)(o + 4) = make_float4(res[4], res[5], res[6], res[7]);
    }
}

extern "C" void kernel_launch(void* const* d_in, const int* in_sizes, int n_in,
                              void* d_out, int out_size, void* d_ws, size_t ws_size,
                              hipStream_t stream) {
    const float* img = (const float*)d_in[0];
    float* out = (float*)d_out;
    const int n_img = in_sizes[0] / (IMG_H * IMG_W);   // = 4
    dim3 grid(GXB * GYB * n_img, 1, 1);                // 4320 blocks
    dim3 block(32, 8, 1);
    fast_score_kernel<<<grid, block, 0, stream>>>(img, out);
}

// Round 2
// 97.040 us; speedup vs baseline: 2.4170x; 2.4170x over previous
//
#include <hip/hip_runtime.h>

#define IMG_H 1080
#define IMG_W 1920
#define TILE_W 128
#define TILE_H 8
#define GXB (IMG_W / TILE_W)   // 15
#define GYB (IMG_H / TILE_H)   // 135
#define BAND_H (TILE_H + 6)    // 14 rows: y0-3 .. y0+10
#define BAND_W 136             // cols gx0-4 .. gx0+131 (taps need gx0-3 .. gx0+130)
#define BAND_W4 (BAND_W / 4)   // 34

// Nonzero iff the 16-bit circular mask has 9 consecutive set bits.
// (Validated absmax=0 in prior rounds; unchanged.)
__device__ __forceinline__ unsigned det9(unsigned m) {
    unsigned x = m | (m << 16);
    unsigned t = x & (x >> 1);   // run 2
    t &= t >> 2;                 // run 4
    t &= t >> 4;                 // run 8
    t &= x >> 8;                 // run 9
    return t;
}

// m = (m << 1) | (val CMP thr) in exactly 2 VALU (v_cmp + v_addc m+m+carry).
#define STEP_GE(m, sc, val, thr)                                          \
    asm("v_cmp_ge_f32 %1, %2, %3\n\tv_addc_co_u32 %0, %1, %0, %0, %1"     \
        : "+v"(m), "=s"(sc) : "v"(val), "v"(thr))
#define STEP_LE(m, sc, val, thr)                                          \
    asm("v_cmp_le_f32 %1, %2, %3\n\tv_addc_co_u32 %0, %1, %0, %0, %1"     \
        : "+v"(m), "=s"(sc) : "v"(val), "v"(thr))

__global__ __launch_bounds__(256) void fast_score_kernel(const float* __restrict__ img,
                                                         float* __restrict__ out) {
    __shared__ float band[BAND_H][BAND_W];   // 7616 B

    // Bijective XCD swizzle (valid for any nwg; m204 form).
    int bid = blockIdx.x;
    {
        const int nwg = gridDim.x;
        const int q = nwg >> 3, r = nwg & 7;
        const int xcd = bid & 7, idx = bid >> 3;
        bid = (xcd < r ? xcd * (q + 1) : r * (q + 1) + (xcd - r) * q) + idx;
    }
    const int bx = bid % GXB;
    const int t0 = bid / GXB;
    const int by = t0 % GYB;
    const int n  = t0 / GYB;

    const int tx  = threadIdx.x;               // 0..127
    const int ty  = threadIdx.y;               // 0..1
    const int tid = ty * TILE_W + tx;          // 0..255

    const int gx0 = bx * TILE_W;
    const int y0  = by * TILE_H;

    const float* base = img + (size_t)n * (IMG_H * IMG_W);

    // ---- stage 14x136 band into LDS (replicate-clamped) ----
    if (bx > 0 && bx < GXB - 1) {
        // Interior: 476 aligned float4 loads (gx0-4 is 16B-aligned), 2 iters/thread.
#pragma unroll
        for (int i = tid; i < BAND_H * BAND_W4; i += 256) {
            const int r = i / BAND_W4;
            const int c = i - r * BAND_W4;
            const int ry = min(max(y0 - 3 + r, 0), IMG_H - 1);
            const float4 v =
                *(const float4*)(base + (size_t)ry * IMG_W + (gx0 - 4 + c * 4));
            *(float4*)&band[r][c * 4] = v;
        }
    } else {
        // x-edge blocks: per-element clamp (block-uniform branch, no divergence).
        for (int i = tid; i < BAND_H * BAND_W; i += 256) {
            const int r  = i / BAND_W;
            const int c  = i - r * BAND_W;
            const int ry = min(max(y0 - 3 + r, 0), IMG_H - 1);
            const int cx = min(max(gx0 - 4 + c, 0), IMG_W - 1);
            band[r][c] = base[(size_t)ry * IMG_W + cx];
        }
    }
    __syncthreads();

    constexpr int DY[16] = {0, 1, 2, 3, 3, 3, 2, 1, 0, -1, -2, -3, -3, -3, -2, -1};
    constexpr int DX[16] = {-3, -3, -2, -1, 0, 1, 2, 3, 3, 3, 2, 1, 0, -1, -2, -3};

    const int cx = tx + 4;   // band col of this thread's pixel column
    float* obase = out + (size_t)n * (IMG_H * IMG_W) + (size_t)y0 * IMG_W + gx0 + tx;

    // 4 pixels per thread, stacked vertically: rows y0 + ty*4 + i.
#pragma unroll
    for (int i = 0; i < 4; ++i) {
        const int j  = ty * 4 + i;   // 0..7 within tile
        const int rr = j + 3;        // band row of the center

        const float center = band[rr][cx];
        const float hi = center + 20.0f;
        const float lo = center - 20.0f;

        // Gather 16 taps (consecutive lanes -> consecutive LDS addrs: conflict-free;
        // same-row tap pairs merge into ds_read2_b32).
        float tv[16];
#pragma unroll
        for (int k = 0; k < 16; ++k) {
            tv[k] = band[rr + DY[k]][cx + DX[k]];
        }

        unsigned dark = 0u, bright = 0u;
        unsigned long long sc0, sc1;
#pragma unroll
        for (int k = 0; k < 16; ++k) {
            STEP_GE(dark,   sc0, tv[k], hi);
            STEP_LE(bright, sc1, tv[k], lo);
        }

        obase[(size_t)j * IMG_W] = (det9(dark) | det9(bright)) ? 1.0f : 0.0f;
    }
}

extern "C" void kernel_launch(void* const* d_in, const int* in_sizes, int n_in,
                              void* d_out, int out_size, void* d_ws, size_t ws_size,
                              hipStream_t stream) {
    const float* img = (const float*)d_in[0];
    float* out = (float*)d_out;
    const int n_img = in_sizes[0] / (IMG_H * IMG_W);   // = 4
    dim3 grid(GXB * GYB * n_img, 1, 1);                // 8100 blocks
    dim3 block(TILE_W, 2, 1);                          // 256 threads
    fast_score_kernel<<<grid, block, 0, stream>>>(img, out);
}